// Round 1
// baseline (41246.527 us; speedup 1.0000x reference)
//
#include <hip/hip_runtime.h>
#include <hip/hip_bf16.h>
#include <stdint.h>

// ESN: out[t] = tanh(U[t] + W_res @ s_{t-1}), T=16384 sequential steps.
// Kernel 1: U = X@W_in^T into d_out in place.
// Kernel 2: 8 worker blocks x 1024 threads claimed on ONE XCD (XCC_ID
// pigeonhole over 64 blocks; claim mechanism proven in r4). Exchange v2:
// 8-byte packets {fp32 value | 32-bit step tag}. Producer: plain
// write-through global_store_dwordx2 (co-L2 proven by runtime probe).
// Consumer: ONE plain SE-scope (sc0) dwordx2 load per thread, tag-checked;
// stragglers/misses fall back to proven L2-atomic tag+value reads, and the
// non-co-L2 topology falls back to agent-scope loads (r5-proven). This
// removes the per-step 8192-atomic polling storm (was ~27 GB/s of atomic
// dirty-line writeback). Gather v2: rows counting-sorted by nnz so each
// wave holds similar-degree rows; gather runs to a wave-uniform
// readfirstlane'd bound over zero-padded slots.

constexpr int T_N = 16384;
constexpr int R_N = 1024;
constexpr int I_N = 128;

// ---------------------------------------------------------------- kernel 1
constexpr int BT = 64, BR = 64;

__global__ __launch_bounds__(256) void gemm_u_kernel(
    const float* __restrict__ X, const float* __restrict__ Win,
    float* __restrict__ U)
{
    __shared__ float XS[BT][68];
    __shared__ float WS[BR][68];
    const int tid = threadIdx.x;
    const int ty = tid >> 4, tx = tid & 15;
    const int t0 = blockIdx.x * BT;
    const int r0 = blockIdx.y * BR;
    float acc[4][4] = {};

    for (int k0 = 0; k0 < I_N; k0 += 64) {
        for (int idx = tid; idx < BT * 16; idx += 256) {
            int row = idx >> 4, c4 = (idx & 15) << 2;
            *reinterpret_cast<float4*>(&XS[row][c4]) =
                *reinterpret_cast<const float4*>(&X[(size_t)(t0 + row) * I_N + k0 + c4]);
        }
        for (int idx = tid; idx < BR * 16; idx += 256) {
            int row = idx >> 4, c4 = (idx & 15) << 2;
            *reinterpret_cast<float4*>(&WS[row][c4]) =
                *reinterpret_cast<const float4*>(&Win[(size_t)(r0 + row) * I_N + k0 + c4]);
        }
        __syncthreads();
#pragma unroll
        for (int k = 0; k < 64; k += 4) {
            float4 a[4], b[4];
#pragma unroll
            for (int i = 0; i < 4; ++i)
                a[i] = *reinterpret_cast<const float4*>(&XS[ty + 16 * i][k]);
#pragma unroll
            for (int jj = 0; jj < 4; ++jj)
                b[jj] = *reinterpret_cast<const float4*>(&WS[tx + 16 * jj][k]);
#pragma unroll
            for (int i = 0; i < 4; ++i)
#pragma unroll
                for (int jj = 0; jj < 4; ++jj)
                    acc[i][jj] += a[i].x * b[jj].x + a[i].y * b[jj].y +
                                  a[i].z * b[jj].z + a[i].w * b[jj].w;
        }
        __syncthreads();
    }
#pragma unroll
    for (int i = 0; i < 4; ++i)
#pragma unroll
        for (int jj = 0; jj < 4; ++jj)
            U[(size_t)(t0 + ty + 16 * i) * R_N + (r0 + tx + 16 * jj)] = acc[i][jj];
}

// ---------------------------------------------------------------- kernel 2
constexpr int GBLK    = 8;             // worker blocks (one XCD)
constexpr int NLAUNCH = 64;            // pigeonhole: some XCD collects 8
constexpr int B2      = 1024;          // 1 slot per thread
constexpr int RPB     = R_N / GBLK;    // 128 rows per block
constexpr int TPR     = 8;             // threads per row
constexpr int KMAX    = 96;            // nnz/row cap (validated r1..r5)
constexpr int NSL     = KMAX / TPR;    // 12 register slots per thread
constexpr int PCAP    = 1 << 20;       // anti-hang cap

__device__ __forceinline__ float fast_tanh(float x) {
    float ax = fabsf(x);
    float e  = __expf(-2.0f * ax);
    float y  = (1.0f - e) / (1.0f + e);
    return copysignf(y, x);
}

// SE-scope atomic add 0 with return: executes at the XCD L2 (never L1-stale)
__device__ __forceinline__ uint32_t l2_atomic_read(uint32_t* addr) {
    uint32_t old;
    asm volatile("global_atomic_add %0, %1, %2, off sc0\n\t"
                 "s_waitcnt vmcnt(0)"
                 : "=v"(old) : "v"(addr), "v"(0u) : "memory");
    return old;
}

// SE-scope plain 8B load: bypasses L1, served by the shared L2
__device__ __forceinline__ unsigned long long l2_load_u64(const void* addr) {
    unsigned long long v;
    asm volatile("global_load_dwordx2 %0, %1, off sc0\n\t"
                 "s_waitcnt vmcnt(0)"
                 : "=v"(v) : "v"(addr) : "memory");
    return v;
}

__global__ __launch_bounds__(1024) void esn_scan_kernel(
    const float* __restrict__ Wres, const float* __restrict__ state0,
    float* out, uint32_t* hdr, unsigned long long* slots)
{
    __shared__ int   s_role, s_fast;
    __shared__ float sbuf[2][R_N];        // 8 KB ping-pong state
    __shared__ uint2 ell[RPB][KMAX];      // 96 KB (col, val-bits)
    __shared__ int   cnt[RPB];
    __shared__ int   rowmap[RPB];         // nnz-ascending row permutation
    __shared__ int   hist[KMAX + 1];      // counting-sort scratch

    const int tid = threadIdx.x;

    // ---- claim: first XCD to collect 8 blocks wins (r4-proven mechanism)
    if (tid == 0) {
        uint32_t xcd;
        asm volatile("s_getreg_b32 %0, hwreg(HW_REG_XCC_ID)" : "=s"(xcd));
        xcd &= 7u;
        uint32_t rank = __hip_atomic_fetch_add(&hdr[xcd], 1u,
                            __ATOMIC_RELAXED, __HIP_MEMORY_SCOPE_AGENT);
        int role = -1;
        if (rank < (uint32_t)GBLK) {
            if (rank == (uint32_t)(GBLK - 1)) {
                uint32_t expected = 0u;
                __hip_atomic_compare_exchange_strong(&hdr[8], &expected, xcd + 1u,
                    __ATOMIC_RELAXED, __ATOMIC_RELAXED, __HIP_MEMORY_SCOPE_AGENT);
            }
            uint32_t win = 0; int sp = 0;
            do {
                win = __hip_atomic_load(&hdr[8], __ATOMIC_RELAXED,
                                        __HIP_MEMORY_SCOPE_AGENT);
            } while (win == 0u && ++sp < PCAP);
            if (win == xcd + 1u) role = (int)rank;
        }
        s_role = role; s_fast = 0;
    }
    __syncthreads();
    const int b = s_role;
    if (b < 0) return;
    const int row0 = b * RPB;

    // ---- co-L2 probe: rank0 dirties a line with a PLAIN store (L2-local,
    // invisible at LLC); workers poll it with SE atomics. Unanimous "seen"
    // proves shared L2 -> enable fast path.
    if (tid == 0) {
        uint32_t* test = hdr + 96;
        if (b == 0) {
            asm volatile("global_store_dword %0, %1, off"
                         :: "v"(test), "v"(0xC0FFEEu) : "memory");
            __hip_atomic_store(&hdr[9], 1u, __ATOMIC_RELAXED,
                               __HIP_MEMORY_SCOPE_AGENT);
        } else {
            int sp = 0;
            while (!__hip_atomic_load(&hdr[9], __ATOMIC_RELAXED,
                                      __HIP_MEMORY_SCOPE_AGENT) && ++sp < PCAP) {}
        }
        uint32_t seen = 0;
        for (int r = 0; r < 32 && !seen; ++r)
            if (l2_atomic_read(test) == 0xC0FFEEu) seen = 1;
        __hip_atomic_store(&hdr[16 + b], seen ? 1u : 2u,
                           __ATOMIC_RELAXED, __HIP_MEMORY_SCOPE_AGENT);
        uint32_t ok = 1;
        for (int i = 0; i < GBLK; ++i) {
            uint32_t v; int sp = 0;
            do { v = __hip_atomic_load(&hdr[16 + i], __ATOMIC_RELAXED,
                                       __HIP_MEMORY_SCOPE_AGENT);
            } while (!v && ++sp < PCAP);
            if (v != 1u) ok = 0;
        }
        s_fast = (int)ok;
    }
    __syncthreads();
    const bool fastp = (s_fast != 0);

    // ---- one-time: extract this block's sparse rows from dense W_res
    if (tid < RPB) cnt[tid] = 0;
    __syncthreads();
    for (int idx = tid; idx < RPB * R_N; idx += B2) {     // coalesced scan
        int r = idx >> 10, c = idx & (R_N - 1);
        float w = Wres[(size_t)(row0 + r) * R_N + c];
        if (w != 0.0f) {
            int slot = atomicAdd(&cnt[r], 1);
            if (slot < KMAX) ell[r][slot] = make_uint2((uint32_t)c, __float_as_uint(w));
        }
    }
    __syncthreads();

    // ---- counting-sort rows by nnz so each wave holds similar-degree rows
    if (tid <= KMAX) hist[tid] = 0;
    __syncthreads();
    if (tid < RPB) atomicAdd(&hist[min(cnt[tid], KMAX)], 1);
    __syncthreads();
    if (tid == 0) {
        int run = 0;
        for (int i = 0; i <= KMAX; ++i) { int c = hist[i]; hist[i] = run; run += c; }
    }
    __syncthreads();
    if (tid < RPB) {
        int c = min(cnt[tid], KMAX);
        int pos = atomicAdd(&hist[c], 1);
        rowmap[pos] = tid;
    }
    __syncthreads();

    // ---- hoist my slots into registers; wave-uniform compact bound kw
    const int rloc = rowmap[tid >> 3];    // permuted local row 0..127
    const int j    = tid & 7;             // 0..7
    const int row  = row0 + rloc;
    int   cols[NSL];
    float vals[NSL];
    int   kw;
    {
        int myn = cnt[rloc];
        if (myn > KMAX) myn = KMAX;
        int kcnt = (myn > j) ? (((myn - 1 - j) >> 3) + 1) : 0;
#pragma unroll
        for (int k = 0; k < NSL; ++k) {
            int slot = j + k * TPR;
            if (slot < myn) {
                uint2 e = ell[rloc][slot];
                cols[k] = (int)e.x;
                vals[k] = __uint_as_float(e.y);
            } else { cols[k] = 0; vals[k] = 0.0f; }  // zero-pad: safe to over-run
        }
        kw = kcnt;
#pragma unroll
        for (int off = 1; off < 64; off <<= 1) {
            int o = __shfl_xor(kw, off, 64);
            kw = (o > kw) ? o : kw;
        }
        kw = __builtin_amdgcn_readfirstlane(kw);   // wave-uniform gather depth
    }

    sbuf[1][tid] = state0[tid];                   // seed parity (t-1)&1 @ t=0
    float u_cur = (j == 0) ? out[row] : 0.0f;
    __syncthreads();

    // ---- sequential scan: tag-checked bulk load -> LDS -> barrier -> gather
    for (int t = 0; t < T_N; ++t) {
        const int p = (t - 1) & 1;

        float u_next = 0.0f;
        if (j == 0 && t + 1 < T_N) u_next = out[(size_t)(t + 1) * R_N + row];

        if (t > 0 && (tid >> 7) != b) {           // own 128 rows already in sbuf
            unsigned long long* slot = slots + ((size_t)p << 10) + tid;
            const uint32_t want = (uint32_t)t;    // s_{t-1} carries tag t
            unsigned long long w = 0;
            bool got = false;
            if (fastp) {
                w = l2_load_u64(slot);            // one coalesced SE-scope load
                got = ((uint32_t)(w >> 32) == want);
                int sp = 0;
                while (!got && ++sp < PCAP) {     // straggler: proven atomic pair
                    uint32_t tg = l2_atomic_read((uint32_t*)slot + 1);
                    if (tg == want) {
                        w = ((unsigned long long)tg << 32) |
                            (unsigned long long)l2_atomic_read((uint32_t*)slot);
                        got = true;
                    }
                }
            }
            if (!got) {                           // agent scope (LLC, r5-proven)
                int sp = 0;
                do {
                    w = __hip_atomic_load(slot, __ATOMIC_RELAXED,
                                          __HIP_MEMORY_SCOPE_AGENT);
                } while ((uint32_t)(w >> 32) != want && ++sp < PCAP);
            }
            sbuf[p][tid] = __uint_as_float((uint32_t)w);
        }
        __syncthreads();                          // sbuf[p] complete

        const float* sb = sbuf[p];
        float acc = 0.0f;
#pragma unroll
        for (int k = 0; k < NSL; ++k) {
            if (k >= kw) break;                   // uniform early exit
            acc = fmaf(vals[k], sb[cols[k]], acc);
        }

        acc += __shfl_xor(acc, 1, TPR);
        acc += __shfl_xor(acc, 2, TPR);
        acc += __shfl_xor(acc, 4, TPR);

        if (j == 0) {
            float y = fast_tanh(u_cur + acc);
            out[(size_t)t * R_N + row] = y;
            sbuf[t & 1][row] = y;                 // local copy for own rows
            unsigned long long w = ((unsigned long long)(uint32_t)(t + 1) << 32)
                                 | (unsigned long long)__float_as_uint(y);
            unsigned long long* slot = slots + ((size_t)(t & 1) << 10) + row;
            if (fastp)
                *(volatile unsigned long long*)slot = w;   // write-through to L2
            else
                __hip_atomic_store(slot, w, __ATOMIC_RELAXED,
                                   __HIP_MEMORY_SCOPE_AGENT);
        }
        u_cur = u_next;
        // parity reuse safety: sbuf[p] is next overwritten at t+2, after the
        // barrier at t+1 which follows every step-t gather; producer's
        // sbuf[t&1] write is read only after barrier(t+1) -> one barrier/step.
    }
}

// ---------------------------------------------------------------- launcher
extern "C" void kernel_launch(void* const* d_in, const int* in_sizes, int n_in,
                              void* d_out, int out_size, void* d_ws, size_t ws_size,
                              hipStream_t stream)
{
    const float* X      = (const float*)d_in[0];   // (T, I)
    const float* W_in   = (const float*)d_in[1];   // (R, I)
    const float* W_res  = (const float*)d_in[2];   // (R, R)
    const float* state0 = (const float*)d_in[3];   // (R,)
    float* out = (float*)d_out;                    // (T, R)

    uint32_t* hdr = (uint32_t*)d_ws;                              // 1 KB header
    unsigned long long* slots =
        (unsigned long long*)((char*)d_ws + 1024);                // 2 x 1024 x 8B

    // zero header + ring tags (harness poisons ws with 0xAA each launch)
    hipMemsetAsync(d_ws, 0, 1024 + (size_t)2 * R_N * sizeof(unsigned long long),
                   stream);

    dim3 g1(T_N / BT, R_N / BR);
    gemm_u_kernel<<<g1, 256, 0, stream>>>(X, W_in, out);

    esn_scan_kernel<<<NLAUNCH, B2, 0, stream>>>(W_res, state0, out, hdr, slots);
}

// Round 2
// 34797.861 us; speedup vs baseline: 1.1853x; 1.1853x over previous
//
#include <hip/hip_runtime.h>
#include <hip/hip_bf16.h>
#include <stdint.h>

// ESN: out[t] = tanh(U[t] + W_res @ s_{t-1}), T=16384 sequential steps.
// Kernel 1: U = X@W_in^T into d_out in place.
// Kernel 2: 8 worker blocks x 1024 threads claimed on ONE XCD via XCC_ID
// pigeonhole (r4-proven). Exchange v3 — NO PROBE, NO AGENT PATH:
// co-L2 is guaranteed by construction (same XCC_ID => same XCD => same L2).
// Producer: 128 plain 8B packet stores {tag|value} (dirty in shared L2),
// barrier-drained, then ONE agent-scope epoch store per block per step
// (producer-store -> consumer-L2-atomic visibility is the r0-proven
// mechanism). Consumers: 7 threads spin on epochs via L2 atomics; after a
// barrier, every thread issues ONE coalesced sc0 (L1-bypass) 8B load,
// tag-checked; mismatch (only possible if sc0 were L1-stale) falls back to
// the coherent L2-atomic pair, which resolves in one iteration. This
// removes both the 8192-atomic/step polling storm (r0, 24.7ms) and the
// agent-spin cliff (r1, 45.2ms: FETCH 225MB of LLC spin traffic).

constexpr int T_N = 16384;
constexpr int R_N = 1024;
constexpr int I_N = 128;

// ---------------------------------------------------------------- kernel 1
constexpr int BT = 64, BR = 64;

__global__ __launch_bounds__(256) void gemm_u_kernel(
    const float* __restrict__ X, const float* __restrict__ Win,
    float* __restrict__ U)
{
    __shared__ float XS[BT][68];
    __shared__ float WS[BR][68];
    const int tid = threadIdx.x;
    const int ty = tid >> 4, tx = tid & 15;
    const int t0 = blockIdx.x * BT;
    const int r0 = blockIdx.y * BR;
    float acc[4][4] = {};

    for (int k0 = 0; k0 < I_N; k0 += 64) {
        for (int idx = tid; idx < BT * 16; idx += 256) {
            int row = idx >> 4, c4 = (idx & 15) << 2;
            *reinterpret_cast<float4*>(&XS[row][c4]) =
                *reinterpret_cast<const float4*>(&X[(size_t)(t0 + row) * I_N + k0 + c4]);
        }
        for (int idx = tid; idx < BR * 16; idx += 256) {
            int row = idx >> 4, c4 = (idx & 15) << 2;
            *reinterpret_cast<float4*>(&WS[row][c4]) =
                *reinterpret_cast<const float4*>(&Win[(size_t)(r0 + row) * I_N + k0 + c4]);
        }
        __syncthreads();
#pragma unroll
        for (int k = 0; k < 64; k += 4) {
            float4 a[4], b[4];
#pragma unroll
            for (int i = 0; i < 4; ++i)
                a[i] = *reinterpret_cast<const float4*>(&XS[ty + 16 * i][k]);
#pragma unroll
            for (int jj = 0; jj < 4; ++jj)
                b[jj] = *reinterpret_cast<const float4*>(&WS[tx + 16 * jj][k]);
#pragma unroll
            for (int i = 0; i < 4; ++i)
#pragma unroll
                for (int jj = 0; jj < 4; ++jj)
                    acc[i][jj] += a[i].x * b[jj].x + a[i].y * b[jj].y +
                                  a[i].z * b[jj].z + a[i].w * b[jj].w;
        }
        __syncthreads();
    }
#pragma unroll
    for (int i = 0; i < 4; ++i)
#pragma unroll
        for (int jj = 0; jj < 4; ++jj)
            U[(size_t)(t0 + ty + 16 * i) * R_N + (r0 + tx + 16 * jj)] = acc[i][jj];
}

// ---------------------------------------------------------------- kernel 2
constexpr int GBLK    = 8;             // worker blocks (one XCD)
constexpr int NLAUNCH = 64;            // pigeonhole: some XCD collects 8
constexpr int B2      = 1024;          // 1 slot per thread
constexpr int RPB     = R_N / GBLK;    // 128 rows per block
constexpr int TPR     = 8;             // threads per row
constexpr int KMAX    = 96;            // nnz/row cap (validated r1..r5)
constexpr int NSL     = KMAX / TPR;    // 12 register slots per thread
constexpr int PCAP    = 1 << 20;       // anti-hang cap

__device__ __forceinline__ float fast_tanh(float x) {
    float ax = fabsf(x);
    float e  = __expf(-2.0f * ax);
    float y  = (1.0f - e) / (1.0f + e);
    return copysignf(y, x);
}

// SE-scope atomic add 0 with return: executes at the XCD L2 (never L1-stale).
// Same-L2 atomics are coherent by L2 serialization (r0-proven fast path).
__device__ __forceinline__ uint32_t l2_atomic_read(uint32_t* addr) {
    uint32_t old;
    asm volatile("global_atomic_add %0, %1, %2, off sc0\n\t"
                 "s_waitcnt vmcnt(0)"
                 : "=v"(old) : "v"(addr), "v"(0u) : "memory");
    return old;
}

// sc0 plain 8B load: bypasses L1, served by the shared L2
__device__ __forceinline__ unsigned long long l2_load_u64(const void* addr) {
    unsigned long long v;
    asm volatile("global_load_dwordx2 %0, %1, off sc0\n\t"
                 "s_waitcnt vmcnt(0)"
                 : "=v"(v) : "v"(addr) : "memory");
    return v;
}

__global__ __launch_bounds__(1024) void esn_scan_kernel(
    const float* __restrict__ Wres, const float* __restrict__ state0,
    float* out, uint32_t* hdr, unsigned long long* slots)
{
    __shared__ int   s_role;
    __shared__ float sbuf[2][R_N];        // 8 KB ping-pong state
    __shared__ uint2 ell[RPB][KMAX];      // 96 KB (col, val-bits)
    __shared__ int   cnt[RPB];
    __shared__ int   rowmap[RPB];         // nnz-ascending row permutation
    __shared__ int   hist[KMAX + 1];      // counting-sort scratch

    const int tid = threadIdx.x;

    // ---- claim: first XCD to collect 8 blocks wins (r4-proven mechanism)
    if (tid == 0) {
        uint32_t xcd;
        asm volatile("s_getreg_b32 %0, hwreg(HW_REG_XCC_ID)" : "=s"(xcd));
        xcd &= 7u;
        uint32_t rank = __hip_atomic_fetch_add(&hdr[xcd], 1u,
                            __ATOMIC_RELAXED, __HIP_MEMORY_SCOPE_AGENT);
        int role = -1;
        if (rank < (uint32_t)GBLK) {
            if (rank == (uint32_t)(GBLK - 1)) {
                uint32_t expected = 0u;
                __hip_atomic_compare_exchange_strong(&hdr[8], &expected, xcd + 1u,
                    __ATOMIC_RELAXED, __ATOMIC_RELAXED, __HIP_MEMORY_SCOPE_AGENT);
            }
            uint32_t win = 0; int sp = 0;
            do {
                win = __hip_atomic_load(&hdr[8], __ATOMIC_RELAXED,
                                        __HIP_MEMORY_SCOPE_AGENT);
            } while (win == 0u && ++sp < PCAP);
            if (win == xcd + 1u) role = (int)rank;
        }
        s_role = role;
    }
    __syncthreads();
    const int b = s_role;
    if (b < 0) return;
    const int row0 = b * RPB;

    // epoch flags: one per block, 64B apart (own cacheline each)
    uint32_t* const epoch = hdr + 32;     // epoch[i] at hdr[32 + 16*i]

    // ---- one-time: extract this block's sparse rows from dense W_res
    if (tid < RPB) cnt[tid] = 0;
    __syncthreads();
    for (int idx = tid; idx < RPB * R_N; idx += B2) {     // coalesced scan
        int r = idx >> 10, c = idx & (R_N - 1);
        float w = Wres[(size_t)(row0 + r) * R_N + c];
        if (w != 0.0f) {
            int slot = atomicAdd(&cnt[r], 1);
            if (slot < KMAX) ell[r][slot] = make_uint2((uint32_t)c, __float_as_uint(w));
        }
    }
    __syncthreads();

    // ---- counting-sort rows by nnz so each wave holds similar-degree rows
    if (tid <= KMAX) hist[tid] = 0;
    __syncthreads();
    if (tid < RPB) atomicAdd(&hist[min(cnt[tid], KMAX)], 1);
    __syncthreads();
    if (tid == 0) {
        int run = 0;
        for (int i = 0; i <= KMAX; ++i) { int c = hist[i]; hist[i] = run; run += c; }
    }
    __syncthreads();
    if (tid < RPB) {
        int c = min(cnt[tid], KMAX);
        int pos = atomicAdd(&hist[c], 1);
        rowmap[pos] = tid;
    }
    __syncthreads();

    // ---- hoist my slots into registers; wave-uniform compact bound kw
    const int rloc = rowmap[tid >> 3];    // permuted local row 0..127
    const int j    = tid & 7;             // 0..7
    const int row  = row0 + rloc;
    int   cols[NSL];
    float vals[NSL];
    int   kw;
    {
        int myn = cnt[rloc];
        if (myn > KMAX) myn = KMAX;
        int kcnt = (myn > j) ? (((myn - 1 - j) >> 3) + 1) : 0;
#pragma unroll
        for (int k = 0; k < NSL; ++k) {
            int slot = j + k * TPR;
            if (slot < myn) {
                uint2 e = ell[rloc][slot];
                cols[k] = (int)e.x;
                vals[k] = __uint_as_float(e.y);
            } else { cols[k] = 0; vals[k] = 0.0f; }  // zero-pad: safe to over-run
        }
        kw = kcnt;
#pragma unroll
        for (int off = 1; off < 64; off <<= 1) {
            int o = __shfl_xor(kw, off, 64);
            kw = (o > kw) ? o : kw;
        }
        kw = __builtin_amdgcn_readfirstlane(kw);   // wave-uniform gather depth
    }

    sbuf[1][tid] = state0[tid];                   // seed parity (t-1)&1 @ t=0
    float u_cur = (j == 0) ? out[row] : 0.0f;
    __syncthreads();

    // ---- sequential scan: drain -> publish -> spin -> load -> gather
    for (int t = 0; t < T_N; ++t) {
        const int p = (t - 1) & 1;

        float u_next = 0.0f;
        if (j == 0 && t + 1 < T_N) u_next = out[(size_t)(t + 1) * R_N + row];

        __syncthreads();                  // B_end: drains iter t-1 packet stores
        if (tid == 0)                     // publish: s_{t-1} complete in L2
            __hip_atomic_store(&epoch[16 * b], (uint32_t)t,
                               __ATOMIC_RELAXED, __HIP_MEMORY_SCOPE_AGENT);
        if (t > 0 && tid < GBLK && tid != b) {
            int sp = 0;                   // 7 spinners/block, L2 atomics
            while (l2_atomic_read(&epoch[16 * tid]) < (uint32_t)t && ++sp < PCAP) {}
        }
        __syncthreads();                  // B1: all remote states in L2

        if (t > 0 && (tid >> 7) != b) {   // own rows already in sbuf
            unsigned long long* slot = slots + ((size_t)p << 10) + tid;
            unsigned long long w = l2_load_u64(slot);   // one coalesced sc0 load
            if ((uint32_t)(w >> 32) != (uint32_t)t) {
                // only reachable if sc0 were L1-stale: coherent atomic pair
                uint32_t tg; int sp = 0;
                do { tg = l2_atomic_read((uint32_t*)slot + 1);
                } while (tg != (uint32_t)t && ++sp < PCAP);
                w = ((unsigned long long)tg << 32) |
                    (unsigned long long)l2_atomic_read((uint32_t*)slot);
            }
            sbuf[p][tid] = __uint_as_float((uint32_t)w);
        }
        __syncthreads();                  // B2: sbuf[p] complete

        const float* sb = sbuf[p];
        float acc = 0.0f;
#pragma unroll
        for (int k = 0; k < NSL; ++k) {
            if (k >= kw) break;           // wave-uniform early exit
            acc = fmaf(vals[k], sb[cols[k]], acc);
        }

        acc += __shfl_xor(acc, 1, TPR);
        acc += __shfl_xor(acc, 2, TPR);
        acc += __shfl_xor(acc, 4, TPR);

        if (j == 0) {
            float y = fast_tanh(u_cur + acc);
            out[(size_t)t * R_N + row] = y;
            sbuf[t & 1][row] = y;                        // own-row fast path
            unsigned long long w = ((unsigned long long)(uint32_t)(t + 1) << 32)
                                 | (unsigned long long)__float_as_uint(y);
            // plain store: dirty line in the SHARED L2 (co-L2 by construction)
            *(volatile unsigned long long*)(slots + ((size_t)(t & 1) << 10) + row) = w;
        }
        u_cur = u_next;
        // sbuf[p] reuse: next overwritten at t+2's load phase, which is
        // beyond B_end(t+1)/B1(t+2) -> every gather(t) read is long done.
    }
}

// ---------------------------------------------------------------- launcher
extern "C" void kernel_launch(void* const* d_in, const int* in_sizes, int n_in,
                              void* d_out, int out_size, void* d_ws, size_t ws_size,
                              hipStream_t stream)
{
    const float* X      = (const float*)d_in[0];   // (T, I)
    const float* W_in   = (const float*)d_in[1];   // (R, I)
    const float* W_res  = (const float*)d_in[2];   // (R, R)
    const float* state0 = (const float*)d_in[3];   // (R,)
    float* out = (float*)d_out;                    // (T, R)

    uint32_t* hdr = (uint32_t*)d_ws;                              // 1 KB header
    unsigned long long* slots =
        (unsigned long long*)((char*)d_ws + 1024);                // 2 x 1024 x 8B

    // zero header + ring slots (harness poisons ws with 0xAA each launch)
    hipMemsetAsync(d_ws, 0, 1024 + (size_t)2 * R_N * sizeof(unsigned long long),
                   stream);

    dim3 g1(T_N / BT, R_N / BR);
    gemm_u_kernel<<<g1, 256, 0, stream>>>(X, W_in, out);

    esn_scan_kernel<<<NLAUNCH, B2, 0, stream>>>(W_res, state0, out, hdr, slots);
}